// Round 1
// baseline (2260.583 us; speedup 1.0000x reference)
//
#include <hip/hip_runtime.h>
#include <hip/hip_bf16.h>
#include <cstdint>
#include <cstddef>

// Problem constants
#define NE   8
#define DIN  1024
#define DH   4096
#define DOUT 1024
#define NTOK 8192

// GEMM tile (m97 structure: 128x128, BK=32, 4 waves, global_load_lds w16)
#define BM 128
#define BN 128
#define BK 32

typedef __attribute__((ext_vector_type(4))) float f32x4;
typedef __attribute__((ext_vector_type(8))) short bf16x8;

typedef const __attribute__((address_space(1))) void gvoid_t;
typedef __attribute__((address_space(3))) void lvoid_t;

__device__ __forceinline__ ushort f2bf(float f) {
  union { float f; unsigned u; } v; v.f = f;
  unsigned r = v.u + 0x7fffu + ((v.u >> 16) & 1u);  // RNE
  return (ushort)(r >> 16);
}

// ---------------- sigma prep: inv_sigma = exp(-ls), sum_ls[e] ----------------
__global__ __launch_bounds__(256) void sigma_prep_kernel(
    const float* __restrict__ lsig, float* __restrict__ inv_sigma,
    float* __restrict__ sum_ls) {
  int e = blockIdx.x, tid = threadIdx.x;
  float part = 0.f;
  for (int d = tid; d < DIN; d += 256) {
    float ls = lsig[e * DIN + d];
    inv_sigma[e * DIN + d] = expf(-ls);
    part += ls;
  }
#pragma unroll
  for (int off = 32; off > 0; off >>= 1) part += __shfl_xor(part, off);
  __shared__ float red[4];
  int wave = tid >> 6, lane = tid & 63;
  if (lane == 0) red[wave] = part;
  __syncthreads();
  if (tid == 0) sum_ls[e] = red[0] + red[1] + red[2] + red[3];
}

// ---------------- router: log_probs, softmax weights, top-2, x->bf16 --------
// one wave per token
__global__ __launch_bounds__(64) void router_kernel(
    const float* __restrict__ x, const float* __restrict__ mus,
    const float* __restrict__ inv_sigma, const float* __restrict__ sum_ls,
    ushort* __restrict__ xbf, float* __restrict__ out_logp,
    float* __restrict__ out_w, float* __restrict__ out_idx) {
  int t = blockIdx.x, lane = threadIdx.x;
  const float* xt = x + (size_t)t * DIN;
  float xv[16];
#pragma unroll
  for (int j = 0; j < 4; ++j) {
    int d0 = j * 256 + lane * 4;
    float4 v = *(const float4*)(xt + d0);
    xv[j * 4 + 0] = v.x; xv[j * 4 + 1] = v.y;
    xv[j * 4 + 2] = v.z; xv[j * 4 + 3] = v.w;
    ushort4 b;
    b.x = f2bf(v.x); b.y = f2bf(v.y); b.z = f2bf(v.z); b.w = f2bf(v.w);
    *(ushort4*)(xbf + (size_t)t * DIN + d0) = b;
  }
  float lp[NE];
#pragma unroll
  for (int e = 0; e < NE; ++e) {
    float acc = 0.f;
#pragma unroll
    for (int j = 0; j < 4; ++j) {
      int d0 = j * 256 + lane * 4;
      float4 mu = *(const float4*)(mus + (size_t)e * DIN + d0);
      float4 is = *(const float4*)(inv_sigma + (size_t)e * DIN + d0);
      float a0 = (xv[j * 4 + 0] - mu.x) * is.x;
      float a1 = (xv[j * 4 + 1] - mu.y) * is.y;
      float a2 = (xv[j * 4 + 2] - mu.z) * is.z;
      float a3 = (xv[j * 4 + 3] - mu.w) * is.w;
      acc += a0 * a0 + a1 * a1 + a2 * a2 + a3 * a3;
    }
#pragma unroll
    for (int off = 32; off > 0; off >>= 1) acc += __shfl_xor(acc, off);
    lp[e] = -0.5f * acc - sum_ls[e];
  }
  if (lane == 0) {
    float m = lp[0];
#pragma unroll
    for (int e = 1; e < NE; ++e) m = fmaxf(m, lp[e]);
    float w[NE], s = 0.f;
#pragma unroll
    for (int e = 0; e < NE; ++e) { w[e] = expf(lp[e] - m); s += w[e]; }
    float inv = 1.f / s;
    int i1 = 0;
#pragma unroll
    for (int e = 1; e < NE; ++e) if (lp[e] > lp[i1]) i1 = e;   // lowest idx on tie
    int i2 = (i1 == 0) ? 1 : 0;
#pragma unroll
    for (int e = 0; e < NE; ++e) if (e != i1 && lp[e] > lp[i2]) i2 = e;
#pragma unroll
    for (int e = 0; e < NE; ++e) {
      out_logp[(size_t)t * NE + e] = lp[e];
      out_w[(size_t)t * NE + e] = w[e] * inv;
    }
    out_idx[(size_t)t * 2 + 0] = (float)i1;  // harness reads d_out as fp32
    out_idx[(size_t)t * 2 + 1] = (float)i2;
  }
}

// ---------------- transpose + fp32->bf16: in [R][C] -> out [C][R] ----------
__global__ __launch_bounds__(256) void transpose_cvt_kernel(
    const float* __restrict__ in, ushort* __restrict__ out, int R, int C) {
  __shared__ float tile[32][33];
  size_t eoff = (size_t)blockIdx.z * (size_t)R * (size_t)C;
  in += eoff; out += eoff;
  int c0 = blockIdx.x * 32, r0 = blockIdx.y * 32;
  int tx = threadIdx.x, ty = threadIdx.y;  // (32,8)
#pragma unroll
  for (int i = 0; i < 4; ++i)
    tile[ty + i * 8][tx] = in[(size_t)(r0 + ty + i * 8) * C + c0 + tx];
  __syncthreads();
#pragma unroll
  for (int i = 0; i < 4; ++i)
    out[(size_t)(c0 + ty + i * 8) * R + r0 + tx] = f2bf(tile[tx][ty + i * 8]);
}

// ---------------- GEMM: C[M][N] = A[M][K] * Bt[N][K]^T, bf16 MFMA ----------
// EP==0: Hout = bf16(gelu_exact(acc + bias))
// EP==1: Fout = w[row,e] * (acc + bias)      (first expert, overwrites poison)
// EP==2: Fout += w[row,e] * (acc + bias)
template <int EP>
__global__ __launch_bounds__(256) void gemm_bt_kernel(
    const ushort* __restrict__ A, const ushort* __restrict__ Bt,
    const float* __restrict__ bias, const float* __restrict__ wgt,
    int expert, ushort* __restrict__ Hout, float* __restrict__ Fout,
    int M, int N, int K) {
  __shared__ __attribute__((aligned(16))) ushort As[BM * BK];
  __shared__ __attribute__((aligned(16))) ushort Bs[BN * BK];
  const int tid = threadIdx.x;
  const int wave = tid >> 6, lane = tid & 63;
  const int m0 = blockIdx.y * BM, n0 = blockIdx.x * BN;
  const int laneM = lane & 15, kg = lane >> 4;
  const int wr = (wave >> 1) * 64, wc = (wave & 1) * 64;
  const int stgRow = lane >> 2;          // 16 rows per gload_lds instr
  const int stgCol = (lane & 3) * 8;     // 4 x 16B per 64B row

  f32x4 acc[4][4];
#pragma unroll
  for (int mi = 0; mi < 4; ++mi)
#pragma unroll
    for (int ni = 0; ni < 4; ++ni)
#pragma unroll
      for (int r = 0; r < 4; ++r) acc[mi][ni][r] = 0.f;

  const int nk = K / BK;
  for (int kt = 0; kt < nk; ++kt) {
#pragma unroll
    for (int i = 0; i < 2; ++i) {
      const int r0 = wave * 32 + i * 16;
      const ushort* ga = A + (size_t)(m0 + r0 + stgRow) * K + kt * BK + stgCol;
      const ushort* gb = Bt + (size_t)(n0 + r0 + stgRow) * K + kt * BK + stgCol;
      __builtin_amdgcn_global_load_lds((gvoid_t*)ga, (lvoid_t*)&As[r0 * BK], 16, 0, 0);
      __builtin_amdgcn_global_load_lds((gvoid_t*)gb, (lvoid_t*)&Bs[r0 * BK], 16, 0, 0);
    }
    __syncthreads();  // compiler emits vmcnt(0) drain before barrier
    bf16x8 af[4], bfr[4];
#pragma unroll
    for (int mi = 0; mi < 4; ++mi)
      af[mi] = *(const bf16x8*)&As[(wr + mi * 16 + laneM) * BK + kg * 8];
#pragma unroll
    for (int ni = 0; ni < 4; ++ni)
      bfr[ni] = *(const bf16x8*)&Bs[(wc + ni * 16 + laneM) * BK + kg * 8];
#pragma unroll
    for (int mi = 0; mi < 4; ++mi)
#pragma unroll
      for (int ni = 0; ni < 4; ++ni)
        acc[mi][ni] = __builtin_amdgcn_mfma_f32_16x16x32_bf16(
            af[mi], bfr[ni], acc[mi][ni], 0, 0, 0);
    __syncthreads();
  }

  // epilogue; C/D layout: col = lane&15, row = (lane>>4)*4 + r  [m89-verified]
#pragma unroll
  for (int mi = 0; mi < 4; ++mi) {
#pragma unroll
    for (int ni = 0; ni < 4; ++ni) {
      const int col = n0 + wc + ni * 16 + laneM;
      const float bv = bias[col];
#pragma unroll
      for (int r = 0; r < 4; ++r) {
        const int row = m0 + wr + mi * 16 + kg * 4 + r;
        const float v = acc[mi][ni][r] + bv;
        if (EP == 0) {
          const float g = 0.5f * v * (1.f + erff(v * 0.70710678118654752f));
          Hout[(size_t)row * N + col] = f2bf(g);
        } else {
          const float wv = wgt[(size_t)row * NE + expert];
          const float o = wv * v;
          if (EP == 1) Fout[(size_t)row * N + col] = o;
          else         Fout[(size_t)row * N + col] += o;
        }
      }
    }
  }
}

extern "C" void kernel_launch(void* const* d_in, const int* in_sizes, int n_in,
                              void* d_out, int out_size, void* d_ws, size_t ws_size,
                              hipStream_t stream) {
  const float* x    = (const float*)d_in[0];
  const float* mus  = (const float*)d_in[1];
  const float* lsig = (const float*)d_in[2];
  const float* W1   = (const float*)d_in[3];
  const float* b1   = (const float*)d_in[4];
  const float* W2   = (const float*)d_in[5];
  const float* b2   = (const float*)d_in[6];

  // outputs concatenated flat (all read back as fp32)
  float* out0 = (float*)d_out;                          // final_output [T][DOUT]
  float* out1 = out0 + (size_t)NTOK * DOUT;             // log_probs [T][E]
  float* out2 = out1 + (size_t)NTOK * NE;               // weights   [T][E]
  float* out3 = out2 + (size_t)NTOK * NE;               // top idx as float [T][2]

  char* ws = (char*)d_ws;
  size_t off = 0;
  ushort* xbf = (ushort*)(ws + off);      off += (size_t)NTOK * DIN * 2;   // 16.8 MB
  ushort* hbuf = (ushort*)(ws + off);     off += (size_t)NTOK * DH * 2;    // 67.1 MB
  float* inv_sigma = (float*)(ws + off);  off += (size_t)NE * DIN * 4;
  float* sum_ls = (float*)(ws + off);     off += 256;
  const size_t slotOff = off;
  const size_t wmatElems = (size_t)DIN * DH;            // per expert, both W1/W2
  const size_t fullNeed = off + (size_t)NE * wmatElems * 2 /*mats*/ * 2 /*bytes*/;
  const bool fullW = ws_size >= fullNeed;

  sigma_prep_kernel<<<NE, 256, 0, stream>>>(lsig, inv_sigma, sum_ls);
  router_kernel<<<NTOK, 64, 0, stream>>>(x, mus, inv_sigma, sum_ls, xbf,
                                         out1, out2, out3);

  ushort* w1t = nullptr; ushort* w2t = nullptr;
  if (fullW) {
    w1t = (ushort*)(ws + slotOff);
    w2t = w1t + (size_t)NE * wmatElems;
    // W1 [E][DIN][DH] -> w1t [E][DH][DIN]; W2 [E][DH][DOUT] -> w2t [E][DOUT][DH]
    transpose_cvt_kernel<<<dim3(DH / 32, DIN / 32, NE), dim3(32, 8), 0, stream>>>(
        W1, w1t, DIN, DH);
    transpose_cvt_kernel<<<dim3(DOUT / 32, DH / 32, NE), dim3(32, 8), 0, stream>>>(
        W2, w2t, DH, DOUT);
  }

  for (int e = 0; e < NE; ++e) {
    const ushort* w1te;
    const ushort* w2te;
    if (fullW) {
      w1te = w1t + (size_t)e * wmatElems;
      w2te = w2t + (size_t)e * wmatElems;
    } else {
      ushort* s1 = (ushort*)(ws + slotOff);
      ushort* s2 = s1 + wmatElems;
      transpose_cvt_kernel<<<dim3(DH / 32, DIN / 32, 1), dim3(32, 8), 0, stream>>>(
          W1 + (size_t)e * wmatElems, s1, DIN, DH);
      transpose_cvt_kernel<<<dim3(DOUT / 32, DH / 32, 1), dim3(32, 8), 0, stream>>>(
          W2 + (size_t)e * wmatElems, s2, DH, DOUT);
      w1te = s1; w2te = s2;
    }
    // GEMM1: h = gelu(x @ W1_e + b1_e)  -> bf16 hbuf [T][DH]
    gemm_bt_kernel<0><<<dim3(DH / BN, NTOK / BM), 256, 0, stream>>>(
        xbf, w1te, b1 + (size_t)e * DH, nullptr, e, hbuf, nullptr,
        NTOK, DH, DIN);
    // GEMM2: out += w[:,e] * (h @ W2_e + b2_e)
    if (e == 0)
      gemm_bt_kernel<1><<<dim3(DOUT / BN, NTOK / BM), 256, 0, stream>>>(
          hbuf, w2te, b2 + (size_t)e * DOUT, out2, e, nullptr, out0,
          NTOK, DOUT, DH);
    else
      gemm_bt_kernel<2><<<dim3(DOUT / BN, NTOK / BM), 256, 0, stream>>>(
          hbuf, w2te, b2 + (size_t)e * DOUT, out2, e, nullptr, out0,
          NTOK, DOUT, DH);
  }
}

// Round 2
// 1248.960 us; speedup vs baseline: 1.8100x; 1.8100x over previous
//
#include <hip/hip_runtime.h>
#include <hip/hip_bf16.h>
#include <cstdint>
#include <cstddef>

// Problem constants
#define NE   8
#define DIN  1024
#define DH   4096
#define DOUT 1024
#define NTOK 8192
#define IDXSTRIDE NTOK
#define CUT 1e-4f

// GEMM tile (m97 structure: 128x128, BK=32, 4 waves, global_load_lds w16)
#define BM 128
#define BN 128
#define BK 32

typedef __attribute__((ext_vector_type(4))) float f32x4;
typedef __attribute__((ext_vector_type(8))) short bf16x8;

typedef const __attribute__((address_space(1))) void gvoid_t;
typedef __attribute__((address_space(3))) void lvoid_t;

__device__ __forceinline__ ushort f2bf(float f) {
  union { float f; unsigned u; } v; v.f = f;
  unsigned r = v.u + 0x7fffu + ((v.u >> 16) & 1u);  // RNE
  return (ushort)(r >> 16);
}

// ---------------- zero out0 + counters ----------------
__global__ __launch_bounds__(256) void zero_kernel(float* __restrict__ out0,
                                                   int* __restrict__ gcnt) {
  size_t n4 = (size_t)NTOK * DOUT / 4;
  float4 z = {0.f, 0.f, 0.f, 0.f};
  for (size_t i = (size_t)blockIdx.x * 256 + threadIdx.x; i < n4;
       i += (size_t)gridDim.x * 256)
    ((float4*)out0)[i] = z;
  if (blockIdx.x == 0 && threadIdx.x < NE) gcnt[threadIdx.x] = 0;
}

// ---------------- sigma prep: inv_sigma = exp(-ls), sum_ls[e] ----------------
__global__ __launch_bounds__(256) void sigma_prep_kernel(
    const float* __restrict__ lsig, float* __restrict__ inv_sigma,
    float* __restrict__ sum_ls) {
  int e = blockIdx.x, tid = threadIdx.x;
  float part = 0.f;
  for (int d = tid; d < DIN; d += 256) {
    float ls = lsig[e * DIN + d];
    inv_sigma[e * DIN + d] = expf(-ls);
    part += ls;
  }
#pragma unroll
  for (int off = 32; off > 0; off >>= 1) part += __shfl_xor(part, off);
  __shared__ float red[4];
  int wave = tid >> 6, lane = tid & 63;
  if (lane == 0) red[wave] = part;
  __syncthreads();
  if (tid == 0) sum_ls[e] = red[0] + red[1] + red[2] + red[3];
}

// ---------------- router: log_probs, softmax weights, top-2, x->bf16 --------
// one wave per token
__global__ __launch_bounds__(64) void router_kernel(
    const float* __restrict__ x, const float* __restrict__ mus,
    const float* __restrict__ inv_sigma, const float* __restrict__ sum_ls,
    ushort* __restrict__ xbf, float* __restrict__ out_logp,
    float* __restrict__ out_w, float* __restrict__ out_idx) {
  int t = blockIdx.x, lane = threadIdx.x;
  const float* xt = x + (size_t)t * DIN;
  float xv[16];
#pragma unroll
  for (int j = 0; j < 4; ++j) {
    int d0 = j * 256 + lane * 4;
    float4 v = *(const float4*)(xt + d0);
    xv[j * 4 + 0] = v.x; xv[j * 4 + 1] = v.y;
    xv[j * 4 + 2] = v.z; xv[j * 4 + 3] = v.w;
    ushort4 b;
    b.x = f2bf(v.x); b.y = f2bf(v.y); b.z = f2bf(v.z); b.w = f2bf(v.w);
    *(ushort4*)(xbf + (size_t)t * DIN + d0) = b;
  }
  float lp[NE];
#pragma unroll
  for (int e = 0; e < NE; ++e) {
    float acc = 0.f;
#pragma unroll
    for (int j = 0; j < 4; ++j) {
      int d0 = j * 256 + lane * 4;
      float4 mu = *(const float4*)(mus + (size_t)e * DIN + d0);
      float4 is = *(const float4*)(inv_sigma + (size_t)e * DIN + d0);
      float a0 = (xv[j * 4 + 0] - mu.x) * is.x;
      float a1 = (xv[j * 4 + 1] - mu.y) * is.y;
      float a2 = (xv[j * 4 + 2] - mu.z) * is.z;
      float a3 = (xv[j * 4 + 3] - mu.w) * is.w;
      acc += a0 * a0 + a1 * a1 + a2 * a2 + a3 * a3;
    }
#pragma unroll
    for (int off = 32; off > 0; off >>= 1) acc += __shfl_xor(acc, off);
    lp[e] = -0.5f * acc - sum_ls[e];
  }
  if (lane == 0) {
    float m = lp[0];
#pragma unroll
    for (int e = 1; e < NE; ++e) m = fmaxf(m, lp[e]);
    float w[NE], s = 0.f;
#pragma unroll
    for (int e = 0; e < NE; ++e) { w[e] = expf(lp[e] - m); s += w[e]; }
    float inv = 1.f / s;
    int i1 = 0;
#pragma unroll
    for (int e = 1; e < NE; ++e) if (lp[e] > lp[i1]) i1 = e;   // lowest idx on tie
    int i2 = (i1 == 0) ? 1 : 0;
#pragma unroll
    for (int e = 0; e < NE; ++e) if (e != i1 && lp[e] > lp[i2]) i2 = e;
#pragma unroll
    for (int e = 0; e < NE; ++e) {
      out_logp[(size_t)t * NE + e] = lp[e];
      out_w[(size_t)t * NE + e] = w[e] * inv;
    }
    out_idx[(size_t)t * 2 + 0] = (float)i1;  // harness reads d_out as fp32
    out_idx[(size_t)t * 2 + 1] = (float)i2;
  }
}

// ---------------- build per-expert token lists (w > CUT) --------------------
// 64 blocks x 128 tokens; LDS-aggregated, 8 global atomics per block
#define TPB_TOK 128
__global__ __launch_bounds__(256) void list_build_kernel(
    const float* __restrict__ w, int* __restrict__ gcnt,
    int* __restrict__ gidx) {
  __shared__ int lcnt[NE];
  __shared__ int lbase[NE];
  __shared__ short llist[NE][TPB_TOK];
  int tid = threadIdx.x;
  if (tid < NE) lcnt[tid] = 0;
  __syncthreads();
  int t0 = blockIdx.x * TPB_TOK;
  if (tid < TPB_TOK) {
#pragma unroll
    for (int e = 0; e < NE; ++e) {
      float wv = w[(size_t)(t0 + tid) * NE + e];
      if (wv > CUT) {
        int p = atomicAdd(&lcnt[e], 1);
        llist[e][p] = (short)tid;
      }
    }
  }
  __syncthreads();
  if (tid < NE) lbase[tid] = atomicAdd(&gcnt[tid], lcnt[tid]);
  __syncthreads();
#pragma unroll
  for (int e = 0; e < NE; ++e)
    for (int j = tid; j < lcnt[e]; j += 256)
      gidx[e * IDXSTRIDE + lbase[e] + j] = t0 + (int)llist[e][j];
}

// ---------------- pad lists to multiple of BM with -1 -----------------------
__global__ __launch_bounds__(64) void pad_kernel(const int* __restrict__ gcnt,
                                                 int* __restrict__ gidx) {
  int e = blockIdx.x;
  int c = gcnt[e];
  int p = (c + BM - 1) & ~(BM - 1);
  for (int j = c + threadIdx.x; j < p; j += 64) gidx[e * IDXSTRIDE + j] = -1;
}

// ---------------- transpose + fp32->bf16: in [R][C] -> out [C][R] ----------
__global__ __launch_bounds__(256) void transpose_cvt_kernel(
    const float* __restrict__ in, ushort* __restrict__ out, int R, int C) {
  __shared__ float tile[32][33];
  size_t eoff = (size_t)blockIdx.z * (size_t)R * (size_t)C;
  in += eoff; out += eoff;
  int c0 = blockIdx.x * 32, r0 = blockIdx.y * 32;
  int tx = threadIdx.x, ty = threadIdx.y;  // (32,8)
#pragma unroll
  for (int i = 0; i < 4; ++i)
    tile[ty + i * 8][tx] = in[(size_t)(r0 + ty + i * 8) * C + c0 + tx];
  __syncthreads();
#pragma unroll
  for (int i = 0; i < 4; ++i)
    out[(size_t)(c0 + ty + i * 8) * R + r0 + tx] = f2bf(tile[tx][ty + i * 8]);
}

// ---------------- GEMM1: h = gelu(gather(x) @ W1t^T + b1) -> compact hbuf ---
__global__ __launch_bounds__(256) void gemm1_kernel(
    const ushort* __restrict__ A, const ushort* __restrict__ Bt,
    const float* __restrict__ bias, const int* __restrict__ gcnt,
    const int* __restrict__ gidx, int expert, ushort* __restrict__ Hout) {
  __shared__ __attribute__((aligned(16))) ushort As[BM * BK];
  __shared__ __attribute__((aligned(16))) ushort Bs[BN * BK];
  const int cnt = gcnt[expert];
  const int m0 = blockIdx.y * BM;
  if (m0 >= ((cnt + BM - 1) & ~(BM - 1))) return;
  const int tid = threadIdx.x, wave = tid >> 6, lane = tid & 63;
  const int n0 = blockIdx.x * BN;
  const int laneM = lane & 15, kg = lane >> 4;
  const int wr = (wave >> 1) * 64, wc = (wave & 1) * 64;
  const int stgRow = lane >> 2, stgCol = (lane & 3) * 8;
  const int rA = wave * 32 + stgRow;
  int tokA = gidx[expert * IDXSTRIDE + m0 + rA];
  int tokB = gidx[expert * IDXSTRIDE + m0 + rA + 16];
  tokA = tokA < 0 ? 0 : tokA;
  tokB = tokB < 0 ? 0 : tokB;
  const ushort* gA0 = A + (size_t)tokA * DIN + stgCol;
  const ushort* gA1 = A + (size_t)tokB * DIN + stgCol;
  const ushort* gB0 = Bt + (size_t)(n0 + rA) * DIN + stgCol;
  const ushort* gB1 = gB0 + (size_t)16 * DIN;

  f32x4 acc[4][4];
#pragma unroll
  for (int mi = 0; mi < 4; ++mi)
#pragma unroll
    for (int ni = 0; ni < 4; ++ni)
#pragma unroll
      for (int r = 0; r < 4; ++r) acc[mi][ni][r] = 0.f;

  for (int kt = 0; kt < DIN / BK; ++kt) {
    const int ko = kt * BK;
    __builtin_amdgcn_global_load_lds((gvoid_t*)(gA0 + ko),
                                     (lvoid_t*)&As[(wave * 32) * BK], 16, 0, 0);
    __builtin_amdgcn_global_load_lds((gvoid_t*)(gA1 + ko),
                                     (lvoid_t*)&As[(wave * 32 + 16) * BK], 16, 0, 0);
    __builtin_amdgcn_global_load_lds((gvoid_t*)(gB0 + ko),
                                     (lvoid_t*)&Bs[(wave * 32) * BK], 16, 0, 0);
    __builtin_amdgcn_global_load_lds((gvoid_t*)(gB1 + ko),
                                     (lvoid_t*)&Bs[(wave * 32 + 16) * BK], 16, 0, 0);
    __syncthreads();
    bf16x8 af[4], bfr[4];
#pragma unroll
    for (int mi = 0; mi < 4; ++mi)
      af[mi] = *(const bf16x8*)&As[(wr + mi * 16 + laneM) * BK + kg * 8];
#pragma unroll
    for (int ni = 0; ni < 4; ++ni)
      bfr[ni] = *(const bf16x8*)&Bs[(wc + ni * 16 + laneM) * BK + kg * 8];
#pragma unroll
    for (int mi = 0; mi < 4; ++mi)
#pragma unroll
      for (int ni = 0; ni < 4; ++ni)
        acc[mi][ni] = __builtin_amdgcn_mfma_f32_16x16x32_bf16(
            af[mi], bfr[ni], acc[mi][ni], 0, 0, 0);
    __syncthreads();
  }

  // C/D layout: col = lane&15, row = (lane>>4)*4 + r  [m89-verified]
#pragma unroll
  for (int mi = 0; mi < 4; ++mi) {
#pragma unroll
    for (int ni = 0; ni < 4; ++ni) {
      const int col = n0 + wc + ni * 16 + laneM;
      const float bv = bias[col];
#pragma unroll
      for (int r = 0; r < 4; ++r) {
        const int row = m0 + wr + mi * 16 + kg * 4 + r;
        const float v = acc[mi][ni][r] + bv;
        const float g = 0.5f * v * (1.f + erff(v * 0.70710678118654752f));
        Hout[(size_t)row * DH + col] = f2bf(g);
      }
    }
  }
}

// ---------------- GEMM2: out0[tok] += w[tok,e]*(h @ W2t^T + b2), split-K=4 --
#define KSPLIT 4
__global__ __launch_bounds__(256) void gemm2_kernel(
    const ushort* __restrict__ H, const ushort* __restrict__ Bt,
    const float* __restrict__ bias, const float* __restrict__ wgt,
    const int* __restrict__ gcnt, const int* __restrict__ gidx, int expert,
    float* __restrict__ out0) {
  __shared__ __attribute__((aligned(16))) ushort As[BM * BK];
  __shared__ __attribute__((aligned(16))) ushort Bs[BN * BK];
  __shared__ int idxLds[BM];
  const int cnt = gcnt[expert];
  const int m0 = blockIdx.y * BM;
  if (m0 >= ((cnt + BM - 1) & ~(BM - 1))) return;
  const int tid = threadIdx.x, wave = tid >> 6, lane = tid & 63;
  const int n0 = blockIdx.x * BN;
  const int ks = blockIdx.z;
  const int kbase = ks * (DH / KSPLIT);
  const int laneM = lane & 15, kg = lane >> 4;
  const int wr = (wave >> 1) * 64, wc = (wave & 1) * 64;
  const int stgRow = lane >> 2, stgCol = (lane & 3) * 8;
  const int rA = wave * 32 + stgRow;
  if (tid < BM) idxLds[tid] = gidx[expert * IDXSTRIDE + m0 + tid];
  const ushort* gA0 = H + (size_t)(m0 + rA) * DH + kbase + stgCol;
  const ushort* gA1 = gA0 + (size_t)16 * DH;
  const ushort* gB0 = Bt + (size_t)(n0 + rA) * DH + kbase + stgCol;
  const ushort* gB1 = gB0 + (size_t)16 * DH;

  f32x4 acc[4][4];
#pragma unroll
  for (int mi = 0; mi < 4; ++mi)
#pragma unroll
    for (int ni = 0; ni < 4; ++ni)
#pragma unroll
      for (int r = 0; r < 4; ++r) acc[mi][ni][r] = 0.f;

  for (int kt = 0; kt < (DH / KSPLIT) / BK; ++kt) {
    const int ko = kt * BK;
    __builtin_amdgcn_global_load_lds((gvoid_t*)(gA0 + ko),
                                     (lvoid_t*)&As[(wave * 32) * BK], 16, 0, 0);
    __builtin_amdgcn_global_load_lds((gvoid_t*)(gA1 + ko),
                                     (lvoid_t*)&As[(wave * 32 + 16) * BK], 16, 0, 0);
    __builtin_amdgcn_global_load_lds((gvoid_t*)(gB0 + ko),
                                     (lvoid_t*)&Bs[(wave * 32) * BK], 16, 0, 0);
    __builtin_amdgcn_global_load_lds((gvoid_t*)(gB1 + ko),
                                     (lvoid_t*)&Bs[(wave * 32 + 16) * BK], 16, 0, 0);
    __syncthreads();
    bf16x8 af[4], bfr[4];
#pragma unroll
    for (int mi = 0; mi < 4; ++mi)
      af[mi] = *(const bf16x8*)&As[(wr + mi * 16 + laneM) * BK + kg * 8];
#pragma unroll
    for (int ni = 0; ni < 4; ++ni)
      bfr[ni] = *(const bf16x8*)&Bs[(wc + ni * 16 + laneM) * BK + kg * 8];
#pragma unroll
    for (int mi = 0; mi < 4; ++mi)
#pragma unroll
      for (int ni = 0; ni < 4; ++ni)
        acc[mi][ni] = __builtin_amdgcn_mfma_f32_16x16x32_bf16(
            af[mi], bfr[ni], acc[mi][ni], 0, 0, 0);
    __syncthreads();
  }

#pragma unroll
  for (int mi = 0; mi < 4; ++mi) {
#pragma unroll
    for (int r = 0; r < 4; ++r) {
      const int row = wr + mi * 16 + kg * 4 + r;
      const int tok = idxLds[row];
      if (tok < 0) continue;
      const float wv = wgt[(size_t)tok * NE + expert];
      float* orow = out0 + (size_t)tok * DOUT;
#pragma unroll
      for (int ni = 0; ni < 4; ++ni) {
        const int col = n0 + wc + ni * 16 + laneM;
        const float v = acc[mi][ni][r] + (ks == 0 ? bias[col] : 0.f);
        atomicAdd(&orow[col], wv * v);
      }
    }
  }
}

extern "C" void kernel_launch(void* const* d_in, const int* in_sizes, int n_in,
                              void* d_out, int out_size, void* d_ws, size_t ws_size,
                              hipStream_t stream) {
  const float* x    = (const float*)d_in[0];
  const float* mus  = (const float*)d_in[1];
  const float* lsig = (const float*)d_in[2];
  const float* W1   = (const float*)d_in[3];
  const float* b1   = (const float*)d_in[4];
  const float* W2   = (const float*)d_in[5];
  const float* b2   = (const float*)d_in[6];

  // outputs concatenated flat (all read back as fp32)
  float* out0 = (float*)d_out;                          // final_output [T][DOUT]
  float* out1 = out0 + (size_t)NTOK * DOUT;             // log_probs [T][E]
  float* out2 = out1 + (size_t)NTOK * NE;               // weights   [T][E]
  float* out3 = out2 + (size_t)NTOK * NE;               // top idx as float [T][2]

  char* ws = (char*)d_ws;
  size_t off = 0;
  ushort* xbf = (ushort*)(ws + off);      off += (size_t)NTOK * DIN * 2;   // 16.8 MB
  ushort* hbuf = (ushort*)(ws + off);     off += (size_t)NTOK * DH * 2;    // 67.1 MB
  float* inv_sigma = (float*)(ws + off);  off += (size_t)NE * DIN * 4;
  float* sum_ls = (float*)(ws + off);     off += 256;
  int* gcnt = (int*)(ws + off);           off += 256;
  int* gidx = (int*)(ws + off);           off += (size_t)NE * IDXSTRIDE * 4;
  const size_t slotOff = off;
  const size_t wmatElems = (size_t)DIN * DH;            // per expert, both W1/W2
  const size_t fullNeed = off + (size_t)NE * wmatElems * 2 /*mats*/ * 2 /*bytes*/;
  const bool fullW = ws_size >= fullNeed;

  zero_kernel<<<2048, 256, 0, stream>>>(out0, gcnt);
  sigma_prep_kernel<<<NE, 256, 0, stream>>>(lsig, inv_sigma, sum_ls);
  router_kernel<<<NTOK, 64, 0, stream>>>(x, mus, inv_sigma, sum_ls, xbf,
                                         out1, out2, out3);
  list_build_kernel<<<NTOK / TPB_TOK, 256, 0, stream>>>(out2, gcnt, gidx);
  pad_kernel<<<NE, 64, 0, stream>>>(gcnt, gidx);

  ushort* w1t = nullptr; ushort* w2t = nullptr;
  if (fullW) {
    w1t = (ushort*)(ws + slotOff);
    w2t = w1t + (size_t)NE * wmatElems;
    // W1 [E][DIN][DH] -> w1t [E][DH][DIN]; W2 [E][DH][DOUT] -> w2t [E][DOUT][DH]
    transpose_cvt_kernel<<<dim3(DH / 32, DIN / 32, NE), dim3(32, 8), 0, stream>>>(
        W1, w1t, DIN, DH);
    transpose_cvt_kernel<<<dim3(DOUT / 32, DH / 32, NE), dim3(32, 8), 0, stream>>>(
        W2, w2t, DH, DOUT);
  }

  for (int e = 0; e < NE; ++e) {
    const ushort* w1te;
    const ushort* w2te;
    if (fullW) {
      w1te = w1t + (size_t)e * wmatElems;
      w2te = w2t + (size_t)e * wmatElems;
    } else {
      ushort* s1 = (ushort*)(ws + slotOff);
      ushort* s2 = s1 + wmatElems;
      transpose_cvt_kernel<<<dim3(DH / 32, DIN / 32, 1), dim3(32, 8), 0, stream>>>(
          W1 + (size_t)e * wmatElems, s1, DIN, DH);
      transpose_cvt_kernel<<<dim3(DOUT / 32, DH / 32, 1), dim3(32, 8), 0, stream>>>(
          W2 + (size_t)e * wmatElems, s2, DH, DOUT);
      w1te = s1; w2te = s2;
    }
    // GEMM1: h = gelu(gather(x) @ W1_e + b1_e) -> compact bf16 hbuf
    gemm1_kernel<<<dim3(DH / BN, NTOK / BM), 256, 0, stream>>>(
        xbf, w1te, b1 + (size_t)e * DH, gcnt, gidx, e, hbuf);
    // GEMM2: out0[tok] += w[tok,e] * (h @ W2_e + b2_e), split-K atomic scatter
    gemm2_kernel<<<dim3(DOUT / BN, NTOK / BM, KSPLIT), 256, 0, stream>>>(
        hbuf, w2te, b2 + (size_t)e * DOUT, out2, gcnt, gidx, e, out0);
  }
}